// Round 1
// baseline (925.676 us; speedup 1.0000x reference)
//
#include <hip/hip_runtime.h>
#include <math.h>

#define NB 32
#define NC 64
#define HW 65536      // 256*256 spatial elements per plane
#define CMID 4
#define NPLANES (NB * NC)   // 2048

// ---------------------------------------------------------------------------
// Kernel 1: per-(b,c)-plane mean.  grid = 2048 blocks, 256 threads.
// Each plane is 65536 floats = 16384 float4; 256 threads -> 64 float4/thread.
// ---------------------------------------------------------------------------
__global__ __launch_bounds__(256) void se_pool(const float* __restrict__ in,
                                               float* __restrict__ pooled) {
    const int plane = blockIdx.x;  // b*NC + c
    const float4* p = (const float4*)(in + (size_t)plane * HW);

    float sum = 0.f;
    #pragma unroll 4
    for (int i = threadIdx.x; i < HW / 4; i += 256) {
        float4 v = p[i];
        sum += (v.x + v.y) + (v.z + v.w);
    }

    // wave64 reduce
    #pragma unroll
    for (int off = 32; off > 0; off >>= 1)
        sum += __shfl_down(sum, off, 64);

    __shared__ float ws[4];
    const int lane = threadIdx.x & 63;
    const int wid  = threadIdx.x >> 6;
    if (lane == 0) ws[wid] = sum;
    __syncthreads();
    if (threadIdx.x == 0) {
        float s = (ws[0] + ws[1]) + (ws[2] + ws[3]);
        pooled[plane] = s * (1.0f / (float)HW);
    }
}

// ---------------------------------------------------------------------------
// Kernel 2: channel MLP 64 -> 4 (relu) -> 64 (sigmoid).  grid = 32, block = 64.
// hidden[b,m] = relu( sum_c pooled[b,c] * w_down[m,c] + b_down[m] )
// scale[b,c]  = sigmoid( sum_m hidden[b,m] * w_up[c,m] + b_up[c] )
// ---------------------------------------------------------------------------
__global__ __launch_bounds__(64) void se_mlp(const float* __restrict__ pooled,
                                             const float* __restrict__ w_down,
                                             const float* __restrict__ b_down,
                                             const float* __restrict__ w_up,
                                             const float* __restrict__ b_up,
                                             float* __restrict__ scale) {
    const int b = blockIdx.x;
    const int t = threadIdx.x;  // 0..63 = channel index

    __shared__ float pb[NC];
    __shared__ float hid[CMID];

    pb[t] = pooled[b * NC + t];
    __syncthreads();

    if (t < CMID) {
        float s = b_down[t];
        #pragma unroll
        for (int c = 0; c < NC; ++c) s += pb[c] * w_down[t * NC + c];
        hid[t] = fmaxf(s, 0.f);
    }
    __syncthreads();

    float s = b_up[t];
    #pragma unroll
    for (int m = 0; m < CMID; ++m) s += hid[m] * w_up[t * CMID + m];
    scale[b * NC + t] = 1.0f / (1.0f + __expf(-s));
}

// ---------------------------------------------------------------------------
// Kernel 3: out[b,c,h,w] = in[b,c,h,w] * scale[b,c].  float4 elementwise.
// Total float4 elements: 32*64*65536/4 = 33,554,432. One float4 per thread.
// plane index = (elem_idx*4) / HW = float4_idx >> 14.
// ---------------------------------------------------------------------------
__global__ __launch_bounds__(256) void se_rescale(const float* __restrict__ in,
                                                  const float* __restrict__ scale,
                                                  float* __restrict__ out) {
    const size_t i = (size_t)blockIdx.x * 256 + threadIdx.x;  // float4 index
    const float s = scale[i >> 14];
    float4 v = ((const float4*)in)[i];
    v.x *= s; v.y *= s; v.z *= s; v.w *= s;
    ((float4*)out)[i] = v;
}

extern "C" void kernel_launch(void* const* d_in, const int* in_sizes, int n_in,
                              void* d_out, int out_size, void* d_ws, size_t ws_size,
                              hipStream_t stream) {
    const float* trans_b = (const float*)d_in[0];
    const float* w_down  = (const float*)d_in[1];
    const float* b_down  = (const float*)d_in[2];
    const float* w_up    = (const float*)d_in[3];
    const float* b_up    = (const float*)d_in[4];
    float* out = (float*)d_out;

    float* pooled = (float*)d_ws;            // 2048 floats
    float* scale  = pooled + NPLANES;        // 2048 floats

    se_pool<<<NPLANES, 256, 0, stream>>>(trans_b, pooled);
    se_mlp<<<NB, 64, 0, stream>>>(pooled, w_down, b_down, w_up, b_up, scale);

    const int n4 = NB * NC * HW / 4;         // 33,554,432 float4
    se_rescale<<<n4 / 256, 256, 0, stream>>>(trans_b, scale, out);
}